// Round 10
// baseline (259.610 us; speedup 1.0000x reference)
//
#include <hip/hip_runtime.h>

typedef unsigned short u16;
typedef unsigned int u32;
typedef __attribute__((ext_vector_type(4))) float f32x4;
typedef __attribute__((ext_vector_type(8))) __bf16 bf16x8;

#define T_SEQ 2048
#define DMODEL 1024
#define NHEAD 16
#define HEADS 64
#define FFDIM 4096
#define MNQ 2097152l  // 2048*1024

__device__ __forceinline__ u16 f2bf(float f) {
  u32 u = __builtin_bit_cast(u32, f);
  u = u + 0x7FFFu + ((u >> 16) & 1u);
  return (u16)(u >> 16);
}
__device__ __forceinline__ float bf2f(u16 h) {
  u32 u = ((u32)h) << 16;
  return __builtin_bit_cast(float, u);
}
__device__ __forceinline__ void gload_lds16(const u16* g, u16* l) {
  __builtin_amdgcn_global_load_lds(
      (const __attribute__((address_space(1))) u32*)g,
      (__attribute__((address_space(3))) u32*)l, 16, 0, 0);
}

// Vectorized 64x64 transpose: float4 loads (1KB/wave), uint4 stores (16B/lane).
__device__ __forceinline__ void transpose64(const float* __restrict__ in,
                                            long ldin, u16* __restrict__ out,
                                            long ldout, int r0, int c0, int tid,
                                            u16* tile) {
#pragma unroll
  for (int p = 0; p < 4; ++p) {
    int idx = p * 256 + tid;
    int r = idx >> 4, c4 = (idx & 15) * 4;
    float4 v = *(const float4*)(in + (long)(r0 + r) * ldin + c0 + c4);
    tile[(c4 + 0) * 66 + r] = f2bf(v.x);
    tile[(c4 + 1) * 66 + r] = f2bf(v.y);
    tile[(c4 + 2) * 66 + r] = f2bf(v.z);
    tile[(c4 + 3) * 66 + r] = f2bf(v.w);
  }
  __syncthreads();
#pragma unroll
  for (int p = 0; p < 2; ++p) {
    int idx = p * 256 + tid;
    int c = idx >> 3, rg = (idx & 7) * 8;
    u16 tmp[8];
#pragma unroll
    for (int j = 0; j < 8; ++j) tmp[j] = tile[c * 66 + rg + j];
    *(uint4*)(out + (long)(c0 + c) * ldout + r0 + rg) = *(uint4*)tmp;
  }
}

// ------------- prep: QKV weight transposes + RMSNorm1 -----------------------
__global__ __launch_bounds__(256) void prep_k(
    const float* __restrict__ Wq, const float* __restrict__ Wk,
    const float* __restrict__ Wv, const float* __restrict__ x,
    const float* __restrict__ g1, u16* __restrict__ QKVwT,
    u16* __restrict__ xn1) {
  __shared__ u16 tile[64 * 66];
  __shared__ float wsum[4];
  int bid = blockIdx.x;
  int tid = threadIdx.x;
  if (bid >= 768) {
    int row = bid - 768;
    const float4* xr = (const float4*)(x + (long)row * DMODEL);
    float4 v = xr[tid];
    float ss = v.x * v.x + v.y * v.y + v.z * v.z + v.w * v.w;
#pragma unroll
    for (int off = 32; off >= 1; off >>= 1) ss += __shfl_xor(ss, off, 64);
    if ((tid & 63) == 0) wsum[tid >> 6] = ss;
    __syncthreads();
    float tot = wsum[0] + wsum[1] + wsum[2] + wsum[3];
    float rms = rsqrtf(tot * (1.0f / DMODEL) + 1e-6f);
    float4 gv = ((const float4*)g1)[tid];
    ushort4 o4 = make_ushort4(f2bf(v.x * rms * gv.x), f2bf(v.y * rms * gv.y),
                              f2bf(v.z * rms * gv.z), f2bf(v.w * rms * gv.w));
    ((ushort4*)(xn1 + (long)row * DMODEL))[tid] = o4;
    return;
  }
  int z = bid >> 4, xi = bid & 15;
  int wsel = z >> 4, h = z & 15;
  const float* in = (wsel == 0 ? Wq : (wsel == 1 ? Wk : Wv)) + (long)h * 65536;
  u16* out = QKVwT + (long)wsel * 1048576 + (long)h * 65536;
  transpose64(in, 64, out, 1024, xi * 64, 0, tid, tile);
}

// ---- fused: proj split-K(x4, bf16 partials) reduce -> x1, RMSNorm -> xn2 ----
__global__ __launch_bounds__(256) void proj_rms_k(
    const u16* __restrict__ part, const float* __restrict__ bias,
    const float* __restrict__ resid, const float* __restrict__ g,
    float* __restrict__ x1, u16* __restrict__ xn2) {
  int row = blockIdx.x;
  int tid = threadIdx.x;
  long i = (long)row * DMODEL + tid * 4;
  float4 r = *(const float4*)(resid + i);
  float4 bi = *(const float4*)(bias + tid * 4);
  float4 v;
  v.x = r.x + bi.x; v.y = r.y + bi.y; v.z = r.z + bi.z; v.w = r.w + bi.w;
#pragma unroll
  for (int z = 0; z < 4; ++z) {
    ushort4 a = *(const ushort4*)(part + z * MNQ + i);
    v.x += bf2f(a.x); v.y += bf2f(a.y); v.z += bf2f(a.z); v.w += bf2f(a.w);
  }
  *(float4*)(x1 + i) = v;
  float ss = v.x * v.x + v.y * v.y + v.z * v.z + v.w * v.w;
#pragma unroll
  for (int off = 32; off >= 1; off >>= 1) ss += __shfl_xor(ss, off, 64);
  __shared__ float wsum[4];
  if ((tid & 63) == 0) wsum[tid >> 6] = ss;
  __syncthreads();
  float tot = wsum[0] + wsum[1] + wsum[2] + wsum[3];
  float rms = rsqrtf(tot * (1.0f / DMODEL) + 1e-6f);
  float4 gv = ((const float4*)g)[tid];
  ushort4 o4 = make_ushort4(f2bf(v.x * rms * gv.x), f2bf(v.y * rms * gv.y),
                            f2bf(v.z * rms * gv.z), f2bf(v.w * rms * gv.w));
  ((ushort4*)(xn2 + (long)row * DMODEL))[tid] = o4;
}

// ------- wide-wave GEMM (R7-best structure) — now used for ALL GEMMs --------
// 128x256 tile, 64x128 wave tile (acc 4x8), 3-stage counted vmcnt(6), 72KB
// LDS, launch_bounds(256,2). LDS bytes/MFMA = 0.56KB (vs 0.75 for 128x128),
// the only lever that measurably improved a GEMM in this session.
// EPI 0: QKV (K=1024, N=3072, bf16 out + V-transpose cols>=2048; FILL blocks
//        past ngemm run W1/W2/Wproj 64x64 transposes).
// EPI 2: FFN1 (K=1024, N=4096, SiLU out).
// EPI 4: FFN2 (Kst=4096, split-K x8 kc=512, N=1024, bf16 partials).
// EPI 5: proj (Kst=1024, split-K x4 kc=256, N=1024, bf16 partials).
template <int EPI, int NITER, bool FILL = false>
__global__ __launch_bounds__(256, 2) void gemm_wide_k(
    const u16* __restrict__ A, const u16* __restrict__ Bt,
    u16* __restrict__ out16, u16* __restrict__ vt,
    u16* __restrict__ p0, u16* __restrict__ p1,
    const float* __restrict__ F1, const float* __restrict__ F2,
    const float* __restrict__ F3, u16* __restrict__ FT1,
    u16* __restrict__ FT2, u16* __restrict__ FT3, int ngemm) {
  __shared__ __align__(16) u16 As[3][128 * 32];
  __shared__ __align__(16) u16 Bs[3][256 * 32];
  if constexpr (FILL) {
    if ((int)blockIdx.x >= ngemm) {
      int tb = (int)blockIdx.x - ngemm;
      u16* tile = (u16*)As;
      const float* in;
      u16* out;
      long ldin, ldout;
      int r0, c0;
      if (tb < 1024) {
        in = F1; out = FT1; ldin = 4096; ldout = 1024;
        r0 = (tb & 15) * 64; c0 = (tb >> 4) * 64;
      } else if (tb < 2048) {
        int b = tb - 1024;
        in = F2; out = FT2; ldin = 1024; ldout = 4096;
        r0 = (b >> 4) * 64; c0 = (b & 15) * 64;
      } else {
        int b = tb - 2048;
        in = F3; out = FT3; ldin = 1024; ldout = 1024;
        r0 = (b >> 4) * 64; c0 = (b & 15) * 64;
      }
      transpose64(in, ldin, out, ldout, r0, c0, threadIdx.x, tile);
      return;
    }
  }
  const int Kst = (EPI == 4) ? 4096 : 1024;  // row stride of A/Bt
  const int N = (EPI == 0) ? 3072 : (EPI == 2) ? 4096 : 1024;
  const int kc = NITER * 32;
  int tid = threadIdx.x;
  int w = tid >> 6, lane = tid & 63;
  int quad = lane >> 4, l15 = lane & 15;
  int wr = w >> 1, wc = w & 1;

  int bid = blockIdx.x;
  int xcd = bid & 7, s = bid >> 3;
  int bx, by, kz;
  if (EPI == 0) {        // 16 m-tiles x 12 n-tiles, no split (s < 24)
    bx = xcd * 2 + (s & 1);
    by = s >> 1;
    kz = 0;
  } else if (EPI == 2) { // 16 m x 16 n (s < 32)
    by = xcd * 2 + (s & 1);
    bx = s >> 1;
    kz = 0;
  } else if (EPI == 4) { // 16 m x 4 n x 8 kz; XCD owns kz (s < 64)
    kz = xcd;
    by = s & 3;
    bx = s >> 2;
  } else {               // EPI 5: 16 m x 4 n x 4 kz (s < 32)
    bx = xcd * 2 + (s & 1);
    by = (s >> 1) & 3;
    kz = s >> 3;
  }
  int m0 = bx * 128, n0 = by * 256;

  f32x4 acc[4][8] = {};

  int lr = lane >> 2;
  int sw = (lr >> 1) & 3;
  int lc = ((lane & 3) ^ sw) * 8;
  const u16* Ak = A + (long)(m0 + w * 32 + lr) * Kst + (long)kz * kc + lc;
  const u16* A2k = Ak + (long)16 * Kst;
  const u16* Bk0 = Bt + (long)(n0 + w * 64 + lr) * Kst + (long)kz * kc + lc;
  const u16* Bk1 = Bk0 + (long)16 * Kst;
  const u16* Bk2 = Bk0 + (long)32 * Kst;
  const u16* Bk3 = Bk0 + (long)48 * Kst;

#pragma unroll
  for (int t = 0; t < 2; ++t) {
    const int off = t * 32;
    gload_lds16(Ak + off, As[t] + w * 1024);
    gload_lds16(A2k + off, As[t] + w * 1024 + 512);
    gload_lds16(Bk0 + off, Bs[t] + w * 2048);
    gload_lds16(Bk1 + off, Bs[t] + w * 2048 + 512);
    gload_lds16(Bk2 + off, Bs[t] + w * 2048 + 1024);
    gload_lds16(Bk3 + off, Bs[t] + w * 2048 + 1536);
  }

  int swq = (l15 >> 1) & 3;
  int qoff = (quad ^ swq) << 3;

#pragma unroll
  for (int k = 0; k < NITER; ++k) {
    const int cb = k % 3;
    if (k + 2 < NITER) {
      asm volatile("s_waitcnt vmcnt(6)\n\ts_barrier" ::: "memory");
      const int pb2 = (k + 2) % 3;
      const int off = (k + 2) * 32;
      gload_lds16(Ak + off, As[pb2] + w * 1024);
      gload_lds16(A2k + off, As[pb2] + w * 1024 + 512);
      gload_lds16(Bk0 + off, Bs[pb2] + w * 2048);
      gload_lds16(Bk1 + off, Bs[pb2] + w * 2048 + 512);
      gload_lds16(Bk2 + off, Bs[pb2] + w * 2048 + 1024);
      gload_lds16(Bk3 + off, Bs[pb2] + w * 2048 + 1536);
    } else if (k + 2 == NITER) {
      asm volatile("s_waitcnt vmcnt(6)\n\ts_barrier" ::: "memory");
    } else {
      asm volatile("s_waitcnt vmcnt(0)\n\ts_barrier" ::: "memory");
    }
    const u16* Ab = As[cb];
    const u16* Bb = Bs[cb];
    bf16x8 af[4], bfr[8];
#pragma unroll
    for (int mt = 0; mt < 4; ++mt)
      af[mt] = *(const bf16x8*)(Ab + (wr * 64 + mt * 16 + l15) * 32 + qoff);
#pragma unroll
    for (int nt = 0; nt < 8; ++nt)
      bfr[nt] = *(const bf16x8*)(Bb + (wc * 128 + nt * 16 + l15) * 32 + qoff);
#pragma unroll
    for (int mt = 0; mt < 4; ++mt)
#pragma unroll
      for (int nt = 0; nt < 8; ++nt)
        acc[mt][nt] = __builtin_amdgcn_mfma_f32_16x16x32_bf16(
            af[mt], bfr[nt], acc[mt][nt], 0, 0, 0);
  }

  u16* pb = nullptr;
  if (EPI == 4)
    pb = (kz < 4) ? (p0 + (long)kz * MNQ) : (p1 + (long)(kz - 4) * MNQ);
  else if (EPI == 5)
    pb = p0 + (long)kz * MNQ;
#pragma unroll
  for (int mt = 0; mt < 4; ++mt)
#pragma unroll
    for (int nt = 0; nt < 8; ++nt) {
      int col = n0 + wc * 128 + nt * 16 + l15;
      if (EPI == 0 && col >= 2048) {
        // V region: write transposed for attention's Vt consumption
        int sc = col - 2048;
        int row0 = m0 + wr * 64 + mt * 16 + quad * 4;
        ushort4 pk = make_ushort4(f2bf(acc[mt][nt][0]), f2bf(acc[mt][nt][1]),
                                  f2bf(acc[mt][nt][2]), f2bf(acc[mt][nt][3]));
        *(ushort4*)(vt + (long)sc * 2048 + row0) = pk;
        continue;
      }
#pragma unroll
      for (int r = 0; r < 4; ++r) {
        int row = m0 + wr * 64 + mt * 16 + quad * 4 + r;
        long idx = (long)row * N + col;
        float v = acc[mt][nt][r];
        if (EPI == 0) {
          out16[idx] = f2bf(v);
        } else if (EPI == 2) {
          out16[idx] = f2bf(v / (1.0f + __expf(-v)));
        } else {
          pb[idx] = f2bf(v);
        }
      }
    }
}

// ---------------- FFN2 split-K(x8) reduce (bf16 partials) ----------------
__global__ __launch_bounds__(256) void reduce_ffn2_k(
    const u16* __restrict__ p0, const u16* __restrict__ p1,
    const float* __restrict__ resid, float* __restrict__ out) {
  long i = ((long)blockIdx.x * 256 + threadIdx.x) * 4;
  float4 r = *(const float4*)(resid + i);
  float4 o = r;
#pragma unroll
  for (int z = 0; z < 4; ++z) {
    ushort4 a = *(const ushort4*)(p0 + z * MNQ + i);
    ushort4 b = *(const ushort4*)(p1 + z * MNQ + i);
    o.x += bf2f(a.x) + bf2f(b.x);
    o.y += bf2f(a.y) + bf2f(b.y);
    o.z += bf2f(a.z) + bf2f(b.z);
    o.w += bf2f(a.w) + bf2f(b.w);
  }
  *(float4*)(out + i) = o;
}

// ------- split-KV flash attention (R6 form — in-loop K/V staging) -----------
#define LSTR 72
__global__ __launch_bounds__(256) void attn_part_k(const u16* __restrict__ QKV,
                                                   const u16* __restrict__ Vt,
                                                   u16* __restrict__ Opart,
                                                   float* __restrict__ lpart,
                                                   u16* __restrict__ attn) {
  __shared__ __align__(16) u16 Qs[64 * LSTR];  // aliased as P after aq read
  __shared__ __align__(16) u16 Ks[64 * LSTR];
  __shared__ __align__(16) u16 Vs[64 * LSTR];
  __shared__ float lbuf[64];

  int tid = threadIdx.x;
  int w = tid >> 6, lane = tid & 63;
  int quad = lane >> 4, l15 = lane & 15;

  int bid = blockIdx.x;
  int xcd = bid & 7, sg = bid >> 3;
  int h = xcd * 2 + (sg & 1);
  int p = sg >> 1;

  int bx = 0, acc0 = 0;
  while (true) {
    int n = (bx >> 3) + 1;
    if (p < acc0 + n) break;
    acc0 += n;
    ++bx;
  }
  int c = p - acc0;
  int t0 = bx * 64;
  int jstart = c * 8;
  int jend = min(jstart + 8, bx + 1);

#pragma unroll
  for (int pp = 0; pp < 2; ++pp) {
    int idx = pp * 256 + tid;
    int row = idx >> 3, cc = idx & 7;
    *(uint4*)(Qs + row * LSTR + cc * 8) =
        *(const uint4*)(QKV + (long)(t0 + row) * 3072 + h * 64 + cc * 8);
  }
  __syncthreads();
  bf16x8 aq[2];
#pragma unroll
  for (int ks = 0; ks < 2; ++ks)
    aq[ks] = *(const bf16x8*)(Qs + (w * 16 + l15) * LSTR + ks * 32 + quad * 8);

  f32x4 oacc[4] = {};
  float lsum = 0.f;
  int qg = t0 + w * 16 + l15;

  u16* PsW = Qs + w * (16 * LSTR);

  for (int j = jstart; j < jend; ++j) {
    __syncthreads();
#pragma unroll
    for (int pp = 0; pp < 2; ++pp) {
      int idx = pp * 256 + tid;
      int row = idx >> 3, cc = idx & 7;
      *(uint4*)(Ks + row * LSTR + cc * 8) =
          *(const uint4*)(QKV + (long)(j * 64 + row) * 3072 + 1024 + h * 64 + cc * 8);
      *(uint4*)(Vs + row * LSTR + cc * 8) =
          *(const uint4*)(Vt + (long)h * (64 * 2048) + (long)row * 2048 + j * 64 + cc * 8);
    }
    __syncthreads();

    f32x4 sacc[4] = {};
#pragma unroll
    for (int ks = 0; ks < 2; ++ks)
#pragma unroll
      for (int ut = 0; ut < 4; ++ut) {
        bf16x8 kf = *(const bf16x8*)(Ks + (ut * 16 + l15) * LSTR + ks * 32 + quad * 8);
        sacc[ut] = __builtin_amdgcn_mfma_f32_16x16x32_bf16(kf, aq[ks], sacc[ut], 0, 0, 0);
      }

    bool boundary = (j == bx);
#pragma unroll
    for (int ut = 0; ut < 4; ++ut) {
      float pv[4];
#pragma unroll
      for (int r = 0; r < 4; ++r) {
        float v = exp2f(sacc[ut][r] * 0.18033688f);
        if (boundary) {
          int u = j * 64 + ut * 16 + quad * 4 + r;
          if (u > qg) v = 0.f;
        }
        pv[r] = v;
        lsum += v;
      }
      ushort4 pk = make_ushort4(f2bf(pv[0]), f2bf(pv[1]), f2bf(pv[2]), f2bf(pv[3]));
      *(ushort4*)(PsW + l15 * LSTR + ut * 16 + quad * 4) = pk;
    }
    asm volatile("s_waitcnt lgkmcnt(0)" ::: "memory");
#pragma unroll
    for (int ks = 0; ks < 2; ++ks) {
      bf16x8 pf = *(const bf16x8*)(PsW + l15 * LSTR + ks * 32 + quad * 8);
#pragma unroll
      for (int ct = 0; ct < 4; ++ct) {
        bf16x8 vf = *(const bf16x8*)(Vs + (ct * 16 + l15) * LSTR + ks * 32 + quad * 8);
        oacc[ct] = __builtin_amdgcn_mfma_f32_16x16x32_bf16(pf, vf, oacc[ct], 0, 0, 0);
      }
    }
  }

  lsum += __shfl_xor(lsum, 16, 64);
  lsum += __shfl_xor(lsum, 32, 64);
  if (quad == 0) lbuf[w * 16 + l15] = 1.0f / lsum;
  asm volatile("s_waitcnt lgkmcnt(0)" ::: "memory");

  float inv[4];
#pragma unroll
  for (int r = 0; r < 4; ++r) inv[r] = lbuf[w * 16 + quad * 4 + r];

  if (bx < 8) {
#pragma unroll
    for (int ct = 0; ct < 4; ++ct)
#pragma unroll
      for (int r = 0; r < 4; ++r)
        attn[(long)(t0 + w * 16 + quad * 4 + r) * 1024 + h * 64 + ct * 16 + l15] =
            f2bf(oacc[ct][r] * inv[r]);
    return;
  }
  long slot = (long)p * 16 + h;
  u16* Ob = Opart + slot * 4096;
#pragma unroll
  for (int ct = 0; ct < 4; ++ct)
#pragma unroll
    for (int r = 0; r < 4; ++r)
      Ob[(w * 16 + quad * 4 + r) * 64 + ct * 16 + l15] = f2bf(oacc[ct][r] * inv[r]);
  if (quad == 0) lpart[slot * 64 + w * 16 + l15] = lsum;
}

// ---------------- combine partials (bx >= 8 only) ----------------
__global__ __launch_bounds__(256) void attn_combine_k(
    const u16* __restrict__ Opart, const float* __restrict__ lpart,
    u16* __restrict__ out) {
  int bx = blockIdx.x + 8, h = blockIdx.y;
  int g = bx >> 3;
  int p0 = 4 * g * (g + 1) + (bx - 8 * g) * (g + 1);
  int nc = g + 1;
  int tid = threadIdx.x;
  int row = tid >> 2, c4 = (tid & 3) * 16;

  float lv[4];
  float wsum = 0.f;
  for (int cidx = 0; cidx < nc; ++cidx) {
    long slot = (long)(p0 + cidx) * 16 + h;
    lv[cidx] = lpart[slot * 64 + row];
    wsum += lv[cidx];
  }
  float rinv = 1.0f / wsum;

  float o[16];
#pragma unroll
  for (int i = 0; i < 16; ++i) o[i] = 0.f;
  for (int cidx = 0; cidx < nc; ++cidx) {
    float wc = lv[cidx] * rinv;
    const u16* Ob = Opart + ((long)(p0 + cidx) * 16 + h) * 4096 + row * 64 + c4;
    bf16x8 a = *(const bf16x8*)Ob;
    bf16x8 b = *(const bf16x8*)(Ob + 8);
#pragma unroll
    for (int i = 0; i < 8; ++i) {
      o[i] += wc * (float)a[i];
      o[8 + i] += wc * (float)b[i];
    }
  }
  u16 ob[16];
#pragma unroll
  for (int i = 0; i < 16; ++i) ob[i] = f2bf(o[i]);
  u16* op = out + (long)(bx * 64 + row) * 1024 + h * 64 + c4;
  *(uint4*)op = *(uint4*)ob;
  *(uint4*)(op + 8) = *(uint4*)(ob + 8);
}

// ---------------- launch ----------------
extern "C" void kernel_launch(void* const* d_in, const int* in_sizes, int n_in,
                              void* d_out, int out_size, void* d_ws, size_t ws_size,
                              hipStream_t stream) {
  const float* x     = (const float*)d_in[0];
  const float* Wq    = (const float*)d_in[1];
  const float* Wk    = (const float*)d_in[2];
  const float* Wv    = (const float*)d_in[3];
  const float* Wproj = (const float*)d_in[4];
  const float* bproj = (const float*)d_in[5];
  const float* W1    = (const float*)d_in[6];
  const float* W2    = (const float*)d_in[7];
  const float* g1    = (const float*)d_in[8];
  const float* g2    = (const float*)d_in[9];

  char* ws = (char*)d_ws;
  u16* QKVwT  = (u16*)(ws);                   // 0..6 MiB
  u16* WprojT = (u16*)(ws + (6ul << 20));     // 6..8
  u16* W1T    = (u16*)(ws + (8ul << 20));     // 8..16
  u16* W2T    = (u16*)(ws + (16ul << 20));    // 16..24 (live thru FFN2)
  u16* xn1    = (u16*)(ws + (24ul << 20));    // 24..28
  u16* QKVb   = (u16*)(ws + (28ul << 20));    // 28..40
  u16* VtB    = (u16*)(ws + (40ul << 20));    // 40..44
  u16* attn   = (u16*)(ws + (44ul << 20));    // 44..48
  float* x1   = (float*)(ws + (48ul << 20));  // 48..56
  u16* xn2    = (u16*)(ws + (56ul << 20));    // 56..60
  u16* hbuf   = (u16*)(ws + (60ul << 20));    // 60..76
  // aliases (dead-region reuse):
  u16* Opart    = (u16*)(ws + (48ul << 20));  // 48..58 (dead before proj_rms)
  float* lpart  = (float*)(ws + (58ul << 20));// 58..58.4
  u16* projp    = (u16*)(ws + (28ul << 20));  // 28..44: 4 x 4 MiB bf16 partials
  u16* ffn2pA   = (u16*)(ws + (28ul << 20));  // 28..44: kz 0..3 (projp dead)
  u16* ffn2pB   = (u16*)(ws);                 // 0..16: kz 4..7 (QKVwT/WprojT/W1T dead)
  if (ws_size < (76ul << 20)) return;

  dim3 blk(256);

  // prep: 768 QKVw transposes + 2048 rmsnorm rows
  prep_k<<<dim3(2816), blk, 0, stream>>>(Wq, Wk, Wv, x, g1, QKVwT, xn1);
  // QKV: 192 wide-gemm blocks (128x256) + 2304 fill (W1, W2, Wproj transposes)
  gemm_wide_k<0, 32, true><<<dim3(2496), blk, 0, stream>>>(
      xn1, QKVwT, QKVb, VtB, nullptr, nullptr,
      W1, W2, Wproj, W1T, W2T, WprojT, 192);
  attn_part_k<<<dim3(1280), blk, 0, stream>>>(QKVb, VtB, Opart, lpart, attn);
  attn_combine_k<<<dim3(24, 16), blk, 0, stream>>>(Opart, lpart, attn);
  // proj: wide 128x256, split-K x4 (kc=256, NITER=8), 256 blocks
  gemm_wide_k<5, 8><<<dim3(256), blk, 0, stream>>>(
      attn, WprojT, nullptr, nullptr, projp, nullptr,
      nullptr, nullptr, nullptr, nullptr, nullptr, nullptr, 0);
  proj_rms_k<<<dim3(2048), blk, 0, stream>>>(projp, bproj, x, g2, x1, xn2);
  // FFN1: wide 128x256, grid 256 (1 block/CU), SiLU fused
  gemm_wide_k<2, 32><<<dim3(256), blk, 0, stream>>>(
      xn2, W1T, hbuf, nullptr, nullptr, nullptr,
      nullptr, nullptr, nullptr, nullptr, nullptr, nullptr, 0);
  // FFN2: wide 128x256, split-K x8 (kc=512), grid 512 (2 blocks/CU)
  gemm_wide_k<4, 16><<<dim3(512), blk, 0, stream>>>(
      hbuf, W2T, nullptr, nullptr, ffn2pA, ffn2pB,
      nullptr, nullptr, nullptr, nullptr, nullptr, nullptr, 0);
  reduce_ffn2_k<<<dim3(2048), blk, 0, stream>>>(ffn2pA, ffn2pB, x1, (float*)d_out);
}

// Round 11
// 253.175 us; speedup vs baseline: 1.0254x; 1.0254x over previous
//
#include <hip/hip_runtime.h>

typedef unsigned short u16;
typedef unsigned int u32;
typedef __attribute__((ext_vector_type(4))) float f32x4;
typedef __attribute__((ext_vector_type(8))) __bf16 bf16x8;

#define T_SEQ 2048
#define DMODEL 1024
#define NHEAD 16
#define HEADS 64
#define FFDIM 4096
#define MNQ 2097152l  // 2048*1024

__device__ __forceinline__ u16 f2bf(float f) {
  u32 u = __builtin_bit_cast(u32, f);
  u = u + 0x7FFFu + ((u >> 16) & 1u);
  return (u16)(u >> 16);
}
__device__ __forceinline__ float bf2f(u16 h) {
  u32 u = ((u32)h) << 16;
  return __builtin_bit_cast(float, u);
}
__device__ __forceinline__ void gload_lds16(const u16* g, u16* l) {
  __builtin_amdgcn_global_load_lds(
      (const __attribute__((address_space(1))) u32*)g,
      (__attribute__((address_space(3))) u32*)l, 16, 0, 0);
}

// Vectorized 64x64 transpose: float4 loads (1KB/wave), uint4 stores (16B/lane).
__device__ __forceinline__ void transpose64(const float* __restrict__ in,
                                            long ldin, u16* __restrict__ out,
                                            long ldout, int r0, int c0, int tid,
                                            u16* tile) {
#pragma unroll
  for (int p = 0; p < 4; ++p) {
    int idx = p * 256 + tid;
    int r = idx >> 4, c4 = (idx & 15) * 4;
    float4 v = *(const float4*)(in + (long)(r0 + r) * ldin + c0 + c4);
    tile[(c4 + 0) * 66 + r] = f2bf(v.x);
    tile[(c4 + 1) * 66 + r] = f2bf(v.y);
    tile[(c4 + 2) * 66 + r] = f2bf(v.z);
    tile[(c4 + 3) * 66 + r] = f2bf(v.w);
  }
  __syncthreads();
#pragma unroll
  for (int p = 0; p < 2; ++p) {
    int idx = p * 256 + tid;
    int c = idx >> 3, rg = (idx & 7) * 8;
    u16 tmp[8];
#pragma unroll
    for (int j = 0; j < 8; ++j) tmp[j] = tile[c * 66 + rg + j];
    *(uint4*)(out + (long)(c0 + c) * ldout + r0 + rg) = *(uint4*)tmp;
  }
}

// ------------- prep (R6 form): QKV/Wproj transposes + RMSNorm1 --------------
__global__ __launch_bounds__(256) void prep_k(
    const float* __restrict__ Wq, const float* __restrict__ Wk,
    const float* __restrict__ Wv, const float* __restrict__ Wproj,
    const float* __restrict__ x, const float* __restrict__ g1,
    u16* __restrict__ QKVwT, u16* __restrict__ WprojT, u16* __restrict__ xn1) {
  __shared__ u16 tile[64 * 66];
  __shared__ float wsum[4];
  int bid = blockIdx.x;
  int tid = threadIdx.x;
  if (bid >= 1024) {
    int row = bid - 1024;
    const float4* xr = (const float4*)(x + (long)row * DMODEL);
    float4 v = xr[tid];
    float ss = v.x * v.x + v.y * v.y + v.z * v.z + v.w * v.w;
#pragma unroll
    for (int off = 32; off >= 1; off >>= 1) ss += __shfl_xor(ss, off, 64);
    if ((tid & 63) == 0) wsum[tid >> 6] = ss;
    __syncthreads();
    float tot = wsum[0] + wsum[1] + wsum[2] + wsum[3];
    float rms = rsqrtf(tot * (1.0f / DMODEL) + 1e-6f);
    float4 gv = ((const float4*)g1)[tid];
    ushort4 o4 = make_ushort4(f2bf(v.x * rms * gv.x), f2bf(v.y * rms * gv.y),
                              f2bf(v.z * rms * gv.z), f2bf(v.w * rms * gv.w));
    ((ushort4*)(xn1 + (long)row * DMODEL))[tid] = o4;
    return;
  }
  const float* in;
  u16* out;
  long ldin, ldout;
  int r0, c0;
  if (bid < 768) {
    int z = bid >> 4, xi = bid & 15;
    int wsel = z >> 4, h = z & 15;
    in = (wsel == 0 ? Wq : (wsel == 1 ? Wk : Wv)) + (long)h * 65536;
    out = QKVwT + (long)wsel * 1048576 + (long)h * 65536;
    ldin = 64; ldout = 1024;
    r0 = xi * 64; c0 = 0;
  } else {
    int b = bid - 768;
    in = Wproj; out = WprojT; ldin = 1024; ldout = 1024;
    r0 = (b >> 4) * 64; c0 = (b & 15) * 64;
  }
  transpose64(in, ldin, out, ldout, r0, c0, tid, tile);
}

// ---- fused: proj split-K(x2, bf16 partials) reduce -> x1, RMSNorm -> xn2 ----
__global__ __launch_bounds__(256) void proj_rms_k(
    const u16* __restrict__ part, const float* __restrict__ bias,
    const float* __restrict__ resid, const float* __restrict__ g,
    float* __restrict__ x1, u16* __restrict__ xn2) {
  int row = blockIdx.x;
  int tid = threadIdx.x;
  long i = (long)row * DMODEL + tid * 4;
  float4 r = *(const float4*)(resid + i);
  float4 bi = *(const float4*)(bias + tid * 4);
  float4 v;
  v.x = r.x + bi.x; v.y = r.y + bi.y; v.z = r.z + bi.z; v.w = r.w + bi.w;
#pragma unroll
  for (int z = 0; z < 2; ++z) {
    ushort4 a = *(const ushort4*)(part + z * MNQ + i);
    v.x += bf2f(a.x); v.y += bf2f(a.y); v.z += bf2f(a.z); v.w += bf2f(a.w);
  }
  *(float4*)(x1 + i) = v;
  float ss = v.x * v.x + v.y * v.y + v.z * v.z + v.w * v.w;
#pragma unroll
  for (int off = 32; off >= 1; off >>= 1) ss += __shfl_xor(ss, off, 64);
  __shared__ float wsum[4];
  if ((tid & 63) == 0) wsum[tid >> 6] = ss;
  __syncthreads();
  float tot = wsum[0] + wsum[1] + wsum[2] + wsum[3];
  float rms = rsqrtf(tot * (1.0f / DMODEL) + 1e-6f);
  float4 gv = ((const float4*)g)[tid];
  ushort4 o4 = make_ushort4(f2bf(v.x * rms * gv.x), f2bf(v.y * rms * gv.y),
                            f2bf(v.z * rms * gv.z), f2bf(v.w * rms * gv.w));
  ((ushort4*)(xn2 + (long)row * DMODEL))[tid] = o4;
}

// ------- GEMM 128x128 (R6 form) — used for proj only ------------------------
// EPI 4: bf16 split-K partial (pb = p0 + kz*MNQ).
template <int EPI, int MODE, int NITER>
__global__ __launch_bounds__(256, 3) void gemm_bt_k(
    const u16* __restrict__ A, const u16* __restrict__ Bt, int N,
    u16* __restrict__ p0) {
  __shared__ __align__(16) u16 As[3][128 * 32];
  __shared__ __align__(16) u16 Bs[3][128 * 32];
  const int K = 1024;
  const int kc = NITER * 32;
  int tid = threadIdx.x;
  int w = tid >> 6, lane = tid & 63;
  int quad = lane >> 4, l15 = lane & 15;
  int wr = w >> 1, wc = w & 1;

  int bid = blockIdx.x;
  int xcd = bid & 7, s = bid >> 3;
  int nn = N >> 7;
  int bx, by, kz;
  {
    int nl = nn >> 3;
    by = xcd * nl + s % nl;
    int r = s / nl;
    bx = r & 15;
    kz = r >> 4;
  }
  int m0 = bx * 128, n0 = by * 128;

  f32x4 acc[4][4] = {};

  int lr = lane >> 2;
  int sw = (lr >> 1) & 3;
  int lc = ((lane & 3) ^ sw) * 8;
  const u16* Ak = A + (long)(m0 + w * 32 + lr) * K + lc + (long)kz * kc;
  const u16* A2k = Ak + (long)16 * K;
  const u16* Bk = Bt + (long)(n0 + w * 32 + lr) * K + lc + (long)kz * kc;
  const u16* B2k = Bk + (long)16 * K;

  gload_lds16(Ak, As[0] + w * 1024);
  gload_lds16(A2k, As[0] + w * 1024 + 512);
  gload_lds16(Bk, Bs[0] + w * 1024);
  gload_lds16(B2k, Bs[0] + w * 1024 + 512);
  gload_lds16(Ak + 32, As[1] + w * 1024);
  gload_lds16(A2k + 32, As[1] + w * 1024 + 512);
  gload_lds16(Bk + 32, Bs[1] + w * 1024);
  gload_lds16(B2k + 32, Bs[1] + w * 1024 + 512);

  int swq = (l15 >> 1) & 3;
  int qoff = (quad ^ swq) << 3;

#pragma unroll
  for (int k = 0; k < NITER; ++k) {
    const int cb = k % 3;
    if (k + 2 < NITER) {
      asm volatile("s_waitcnt vmcnt(4)\n\ts_barrier" ::: "memory");
      const int pb = (k + 2) % 3;
      const int off = (k + 2) * 32;
      gload_lds16(Ak + off, As[pb] + w * 1024);
      gload_lds16(A2k + off, As[pb] + w * 1024 + 512);
      gload_lds16(Bk + off, Bs[pb] + w * 1024);
      gload_lds16(B2k + off, Bs[pb] + w * 1024 + 512);
    } else {
      asm volatile("s_waitcnt vmcnt(0)\n\ts_barrier" ::: "memory");
    }
    const u16* Ab = As[cb];
    const u16* Bb = Bs[cb];
    bf16x8 af[4], bfr[4];
#pragma unroll
    for (int mt = 0; mt < 4; ++mt)
      af[mt] = *(const bf16x8*)(Ab + (wr * 64 + mt * 16 + l15) * 32 + qoff);
#pragma unroll
    for (int nt = 0; nt < 4; ++nt)
      bfr[nt] = *(const bf16x8*)(Bb + (wc * 64 + nt * 16 + l15) * 32 + qoff);
#pragma unroll
    for (int mt = 0; mt < 4; ++mt)
#pragma unroll
      for (int nt = 0; nt < 4; ++nt)
        acc[mt][nt] = __builtin_amdgcn_mfma_f32_16x16x32_bf16(
            af[mt], bfr[nt], acc[mt][nt], 0, 0, 0);
  }

  u16* pb = p0 + (long)kz * MNQ;
#pragma unroll
  for (int mt = 0; mt < 4; ++mt)
#pragma unroll
    for (int nt = 0; nt < 4; ++nt) {
      int col = n0 + wc * 64 + nt * 16 + l15;
#pragma unroll
      for (int r = 0; r < 4; ++r) {
        int row = m0 + wr * 64 + mt * 16 + quad * 4 + r;
        pb[(long)row * N + col] = f2bf(acc[mt][nt][r]);
      }
    }
}

// ------- wide-wave GEMM: 128x256 tile, 64x128 wave tile ---------------------
// EPI 0: QKV (K=1024, N=3072, bf16 out + V-transpose cols>=2048; FILL blocks
//        past ngemm run W1/W2 64x64 transposes).
// EPI 2: FFN1 (K=1024, N=4096, SiLU out).
// EPI 4: FFN2 (Kst=4096, split-K x8 kc=512, N=1024, bf16 partials).
template <int EPI, int NITER, bool FILL = false>
__global__ __launch_bounds__(256, 2) void gemm_wide_k(
    const u16* __restrict__ A, const u16* __restrict__ Bt,
    u16* __restrict__ out16, u16* __restrict__ vt,
    u16* __restrict__ p0, u16* __restrict__ p1,
    const float* __restrict__ F1, const float* __restrict__ F2,
    u16* __restrict__ FT1, u16* __restrict__ FT2, int ngemm) {
  __shared__ __align__(16) u16 As[3][128 * 32];
  __shared__ __align__(16) u16 Bs[3][256 * 32];
  if constexpr (FILL) {
    if ((int)blockIdx.x >= ngemm) {
      int tb = (int)blockIdx.x - ngemm;
      u16* tile = (u16*)As;
      const float* in;
      u16* out;
      long ldin, ldout;
      int r0, c0;
      if (tb < 1024) {
        in = F1; out = FT1; ldin = 4096; ldout = 1024;
        r0 = (tb & 15) * 64; c0 = (tb >> 4) * 64;
      } else {
        int b = tb - 1024;
        in = F2; out = FT2; ldin = 1024; ldout = 4096;
        r0 = (b >> 4) * 64; c0 = (b & 15) * 64;
      }
      transpose64(in, ldin, out, ldout, r0, c0, threadIdx.x, tile);
      return;
    }
  }
  const int Kst = (EPI == 4) ? 4096 : 1024;  // row stride of A/Bt
  const int N = (EPI == 0) ? 3072 : (EPI == 2) ? 4096 : 1024;
  const int kc = NITER * 32;
  int tid = threadIdx.x;
  int w = tid >> 6, lane = tid & 63;
  int quad = lane >> 4, l15 = lane & 15;
  int wr = w >> 1, wc = w & 1;

  int bid = blockIdx.x;
  int xcd = bid & 7, s = bid >> 3;
  int bx, by, kz;
  if (EPI == 0) {        // 16 m-tiles x 12 n-tiles (s < 24)
    bx = xcd * 2 + (s & 1);
    by = s >> 1;
    kz = 0;
  } else if (EPI == 2) { // 16 m x 16 n (s < 32)
    by = xcd * 2 + (s & 1);
    bx = s >> 1;
    kz = 0;
  } else {               // EPI 4: 16 m x 4 n x 8 kz; XCD owns kz (s < 64)
    kz = xcd;
    by = s & 3;
    bx = s >> 2;
  }
  int m0 = bx * 128, n0 = by * 256;

  f32x4 acc[4][8] = {};

  int lr = lane >> 2;
  int sw = (lr >> 1) & 3;
  int lc = ((lane & 3) ^ sw) * 8;
  const u16* Ak = A + (long)(m0 + w * 32 + lr) * Kst + (long)kz * kc + lc;
  const u16* A2k = Ak + (long)16 * Kst;
  const u16* Bk0 = Bt + (long)(n0 + w * 64 + lr) * Kst + (long)kz * kc + lc;
  const u16* Bk1 = Bk0 + (long)16 * Kst;
  const u16* Bk2 = Bk0 + (long)32 * Kst;
  const u16* Bk3 = Bk0 + (long)48 * Kst;

#pragma unroll
  for (int t = 0; t < 2; ++t) {
    const int off = t * 32;
    gload_lds16(Ak + off, As[t] + w * 1024);
    gload_lds16(A2k + off, As[t] + w * 1024 + 512);
    gload_lds16(Bk0 + off, Bs[t] + w * 2048);
    gload_lds16(Bk1 + off, Bs[t] + w * 2048 + 512);
    gload_lds16(Bk2 + off, Bs[t] + w * 2048 + 1024);
    gload_lds16(Bk3 + off, Bs[t] + w * 2048 + 1536);
  }

  int swq = (l15 >> 1) & 3;
  int qoff = (quad ^ swq) << 3;

#pragma unroll
  for (int k = 0; k < NITER; ++k) {
    const int cb = k % 3;
    if (k + 2 < NITER) {
      asm volatile("s_waitcnt vmcnt(6)\n\ts_barrier" ::: "memory");
      const int pb2 = (k + 2) % 3;
      const int off = (k + 2) * 32;
      gload_lds16(Ak + off, As[pb2] + w * 1024);
      gload_lds16(A2k + off, As[pb2] + w * 1024 + 512);
      gload_lds16(Bk0 + off, Bs[pb2] + w * 2048);
      gload_lds16(Bk1 + off, Bs[pb2] + w * 2048 + 512);
      gload_lds16(Bk2 + off, Bs[pb2] + w * 2048 + 1024);
      gload_lds16(Bk3 + off, Bs[pb2] + w * 2048 + 1536);
    } else if (k + 2 == NITER) {
      asm volatile("s_waitcnt vmcnt(6)\n\ts_barrier" ::: "memory");
    } else {
      asm volatile("s_waitcnt vmcnt(0)\n\ts_barrier" ::: "memory");
    }
    const u16* Ab = As[cb];
    const u16* Bb = Bs[cb];
    bf16x8 af[4], bfr[8];
#pragma unroll
    for (int mt = 0; mt < 4; ++mt)
      af[mt] = *(const bf16x8*)(Ab + (wr * 64 + mt * 16 + l15) * 32 + qoff);
#pragma unroll
    for (int nt = 0; nt < 8; ++nt)
      bfr[nt] = *(const bf16x8*)(Bb + (wc * 128 + nt * 16 + l15) * 32 + qoff);
#pragma unroll
    for (int mt = 0; mt < 4; ++mt)
#pragma unroll
      for (int nt = 0; nt < 8; ++nt)
        acc[mt][nt] = __builtin_amdgcn_mfma_f32_16x16x32_bf16(
            af[mt], bfr[nt], acc[mt][nt], 0, 0, 0);
  }

  u16* pb = nullptr;
  if (EPI == 4)
    pb = (kz < 4) ? (p0 + (long)kz * MNQ) : (p1 + (long)(kz - 4) * MNQ);
#pragma unroll
  for (int mt = 0; mt < 4; ++mt)
#pragma unroll
    for (int nt = 0; nt < 8; ++nt) {
      int col = n0 + wc * 128 + nt * 16 + l15;
      if (EPI == 0 && col >= 2048) {
        // V region: write transposed for attention's Vt consumption
        int sc = col - 2048;
        int row0 = m0 + wr * 64 + mt * 16 + quad * 4;
        ushort4 pk = make_ushort4(f2bf(acc[mt][nt][0]), f2bf(acc[mt][nt][1]),
                                  f2bf(acc[mt][nt][2]), f2bf(acc[mt][nt][3]));
        *(ushort4*)(vt + (long)sc * 2048 + row0) = pk;
        continue;
      }
#pragma unroll
      for (int r = 0; r < 4; ++r) {
        int row = m0 + wr * 64 + mt * 16 + quad * 4 + r;
        long idx = (long)row * N + col;
        float v = acc[mt][nt][r];
        if (EPI == 0) {
          out16[idx] = f2bf(v);
        } else if (EPI == 2) {
          out16[idx] = f2bf(v / (1.0f + __expf(-v)));
        } else {
          pb[idx] = f2bf(v);
        }
      }
    }
}

// ---------------- FFN2 split-K(x8) reduce (bf16 partials) ----------------
__global__ __launch_bounds__(256) void reduce_ffn2_k(
    const u16* __restrict__ p0, const u16* __restrict__ p1,
    const float* __restrict__ resid, float* __restrict__ out) {
  long i = ((long)blockIdx.x * 256 + threadIdx.x) * 4;
  float4 r = *(const float4*)(resid + i);
  float4 o = r;
#pragma unroll
  for (int z = 0; z < 4; ++z) {
    ushort4 a = *(const ushort4*)(p0 + z * MNQ + i);
    ushort4 b = *(const ushort4*)(p1 + z * MNQ + i);
    o.x += bf2f(a.x) + bf2f(b.x);
    o.y += bf2f(a.y) + bf2f(b.y);
    o.z += bf2f(a.z) + bf2f(b.z);
    o.w += bf2f(a.w) + bf2f(b.w);
  }
  *(float4*)(out + i) = o;
}

// ------- split-KV flash attention (R6 form — in-loop K/V staging) -----------
#define LSTR 72
__global__ __launch_bounds__(256) void attn_part_k(const u16* __restrict__ QKV,
                                                   const u16* __restrict__ Vt,
                                                   u16* __restrict__ Opart,
                                                   float* __restrict__ lpart,
                                                   u16* __restrict__ attn) {
  __shared__ __align__(16) u16 Qs[64 * LSTR];  // aliased as P after aq read
  __shared__ __align__(16) u16 Ks[64 * LSTR];
  __shared__ __align__(16) u16 Vs[64 * LSTR];
  __shared__ float lbuf[64];

  int tid = threadIdx.x;
  int w = tid >> 6, lane = tid & 63;
  int quad = lane >> 4, l15 = lane & 15;

  int bid = blockIdx.x;
  int xcd = bid & 7, sg = bid >> 3;
  int h = xcd * 2 + (sg & 1);
  int p = sg >> 1;

  int bx = 0, acc0 = 0;
  while (true) {
    int n = (bx >> 3) + 1;
    if (p < acc0 + n) break;
    acc0 += n;
    ++bx;
  }
  int c = p - acc0;
  int t0 = bx * 64;
  int jstart = c * 8;
  int jend = min(jstart + 8, bx + 1);

#pragma unroll
  for (int pp = 0; pp < 2; ++pp) {
    int idx = pp * 256 + tid;
    int row = idx >> 3, cc = idx & 7;
    *(uint4*)(Qs + row * LSTR + cc * 8) =
        *(const uint4*)(QKV + (long)(t0 + row) * 3072 + h * 64 + cc * 8);
  }
  __syncthreads();
  bf16x8 aq[2];
#pragma unroll
  for (int ks = 0; ks < 2; ++ks)
    aq[ks] = *(const bf16x8*)(Qs + (w * 16 + l15) * LSTR + ks * 32 + quad * 8);

  f32x4 oacc[4] = {};
  float lsum = 0.f;
  int qg = t0 + w * 16 + l15;

  u16* PsW = Qs + w * (16 * LSTR);

  for (int j = jstart; j < jend; ++j) {
    __syncthreads();
#pragma unroll
    for (int pp = 0; pp < 2; ++pp) {
      int idx = pp * 256 + tid;
      int row = idx >> 3, cc = idx & 7;
      *(uint4*)(Ks + row * LSTR + cc * 8) =
          *(const uint4*)(QKV + (long)(j * 64 + row) * 3072 + 1024 + h * 64 + cc * 8);
      *(uint4*)(Vs + row * LSTR + cc * 8) =
          *(const uint4*)(Vt + (long)h * (64 * 2048) + (long)row * 2048 + j * 64 + cc * 8);
    }
    __syncthreads();

    f32x4 sacc[4] = {};
#pragma unroll
    for (int ks = 0; ks < 2; ++ks)
#pragma unroll
      for (int ut = 0; ut < 4; ++ut) {
        bf16x8 kf = *(const bf16x8*)(Ks + (ut * 16 + l15) * LSTR + ks * 32 + quad * 8);
        sacc[ut] = __builtin_amdgcn_mfma_f32_16x16x32_bf16(kf, aq[ks], sacc[ut], 0, 0, 0);
      }

    bool boundary = (j == bx);
#pragma unroll
    for (int ut = 0; ut < 4; ++ut) {
      float pv[4];
#pragma unroll
      for (int r = 0; r < 4; ++r) {
        float v = exp2f(sacc[ut][r] * 0.18033688f);
        if (boundary) {
          int u = j * 64 + ut * 16 + quad * 4 + r;
          if (u > qg) v = 0.f;
        }
        pv[r] = v;
        lsum += v;
      }
      ushort4 pk = make_ushort4(f2bf(pv[0]), f2bf(pv[1]), f2bf(pv[2]), f2bf(pv[3]));
      *(ushort4*)(PsW + l15 * LSTR + ut * 16 + quad * 4) = pk;
    }
    asm volatile("s_waitcnt lgkmcnt(0)" ::: "memory");
#pragma unroll
    for (int ks = 0; ks < 2; ++ks) {
      bf16x8 pf = *(const bf16x8*)(PsW + l15 * LSTR + ks * 32 + quad * 8);
#pragma unroll
      for (int ct = 0; ct < 4; ++ct) {
        bf16x8 vf = *(const bf16x8*)(Vs + (ct * 16 + l15) * LSTR + ks * 32 + quad * 8);
        oacc[ct] = __builtin_amdgcn_mfma_f32_16x16x32_bf16(pf, vf, oacc[ct], 0, 0, 0);
      }
    }
  }

  lsum += __shfl_xor(lsum, 16, 64);
  lsum += __shfl_xor(lsum, 32, 64);
  if (quad == 0) lbuf[w * 16 + l15] = 1.0f / lsum;
  asm volatile("s_waitcnt lgkmcnt(0)" ::: "memory");

  float inv[4];
#pragma unroll
  for (int r = 0; r < 4; ++r) inv[r] = lbuf[w * 16 + quad * 4 + r];

  if (bx < 8) {
#pragma unroll
    for (int ct = 0; ct < 4; ++ct)
#pragma unroll
      for (int r = 0; r < 4; ++r)
        attn[(long)(t0 + w * 16 + quad * 4 + r) * 1024 + h * 64 + ct * 16 + l15] =
            f2bf(oacc[ct][r] * inv[r]);
    return;
  }
  long slot = (long)p * 16 + h;
  u16* Ob = Opart + slot * 4096;
#pragma unroll
  for (int ct = 0; ct < 4; ++ct)
#pragma unroll
    for (int r = 0; r < 4; ++r)
      Ob[(w * 16 + quad * 4 + r) * 64 + ct * 16 + l15] = f2bf(oacc[ct][r] * inv[r]);
  if (quad == 0) lpart[slot * 64 + w * 16 + l15] = lsum;
}

// ---------------- combine partials (bx >= 8 only) ----------------
__global__ __launch_bounds__(256) void attn_combine_k(
    const u16* __restrict__ Opart, const float* __restrict__ lpart,
    u16* __restrict__ out) {
  int bx = blockIdx.x + 8, h = blockIdx.y;
  int g = bx >> 3;
  int p0 = 4 * g * (g + 1) + (bx - 8 * g) * (g + 1);
  int nc = g + 1;
  int tid = threadIdx.x;
  int row = tid >> 2, c4 = (tid & 3) * 16;

  float lv[4];
  float wsum = 0.f;
  for (int cidx = 0; cidx < nc; ++cidx) {
    long slot = (long)(p0 + cidx) * 16 + h;
    lv[cidx] = lpart[slot * 64 + row];
    wsum += lv[cidx];
  }
  float rinv = 1.0f / wsum;

  float o[16];
#pragma unroll
  for (int i = 0; i < 16; ++i) o[i] = 0.f;
  for (int cidx = 0; cidx < nc; ++cidx) {
    float wc = lv[cidx] * rinv;
    const u16* Ob = Opart + ((long)(p0 + cidx) * 16 + h) * 4096 + row * 64 + c4;
    bf16x8 a = *(const bf16x8*)Ob;
    bf16x8 b = *(const bf16x8*)(Ob + 8);
#pragma unroll
    for (int i = 0; i < 8; ++i) {
      o[i] += wc * (float)a[i];
      o[8 + i] += wc * (float)b[i];
    }
  }
  u16 ob[16];
#pragma unroll
  for (int i = 0; i < 16; ++i) ob[i] = f2bf(o[i]);
  u16* op = out + (long)(bx * 64 + row) * 1024 + h * 64 + c4;
  *(uint4*)op = *(uint4*)ob;
  *(uint4*)(op + 8) = *(uint4*)(ob + 8);
}

// ---------------- launch ----------------
extern "C" void kernel_launch(void* const* d_in, const int* in_sizes, int n_in,
                              void* d_out, int out_size, void* d_ws, size_t ws_size,
                              hipStream_t stream) {
  const float* x     = (const float*)d_in[0];
  const float* Wq    = (const float*)d_in[1];
  const float* Wk    = (const float*)d_in[2];
  const float* Wv    = (const float*)d_in[3];
  const float* Wproj = (const float*)d_in[4];
  const float* bproj = (const float*)d_in[5];
  const float* W1    = (const float*)d_in[6];
  const float* W2    = (const float*)d_in[7];
  const float* g1    = (const float*)d_in[8];
  const float* g2    = (const float*)d_in[9];

  char* ws = (char*)d_ws;
  u16* QKVwT  = (u16*)(ws);                   // 0..6 MiB
  u16* WprojT = (u16*)(ws + (6ul << 20));     // 6..8
  u16* W1T    = (u16*)(ws + (8ul << 20));     // 8..16
  u16* W2T    = (u16*)(ws + (16ul << 20));    // 16..24 (live thru FFN2)
  u16* xn1    = (u16*)(ws + (24ul << 20));    // 24..28
  u16* QKVb   = (u16*)(ws + (28ul << 20));    // 28..40
  u16* VtB    = (u16*)(ws + (40ul << 20));    // 40..44
  u16* attn   = (u16*)(ws + (44ul << 20));    // 44..48
  float* x1   = (float*)(ws + (48ul << 20));  // 48..56
  u16* xn2    = (u16*)(ws + (56ul << 20));    // 56..60
  u16* hbuf   = (u16*)(ws + (60ul << 20));    // 60..76
  // aliases (dead-region reuse):
  u16* Opart    = (u16*)(ws + (48ul << 20));  // 48..58 (dead before proj_rms)
  float* lpart  = (float*)(ws + (58ul << 20));// 58..58.4
  u16* projp    = (u16*)(ws + (28ul << 20));  // 28..36: 2 x 4 MiB bf16 partials
  u16* ffn2pA   = (u16*)(ws + (28ul << 20));  // 28..44: kz 0..3 (projp dead)
  u16* ffn2pB   = (u16*)(ws);                 // 0..16: kz 4..7 (weights dead)
  if (ws_size < (76ul << 20)) return;

  dim3 blk(256);

  // prep: 768 QKVw + 256 Wproj transposes + 2048 rmsnorm rows (R6 form)
  prep_k<<<dim3(3072), blk, 0, stream>>>(
      Wq, Wk, Wv, Wproj, x, g1, QKVwT, WprojT, xn1);
  // QKV: 192 wide-gemm blocks (128x256) + 2048 fill (W1/W2 transposes)
  gemm_wide_k<0, 32, true><<<dim3(2240), blk, 0, stream>>>(
      xn1, QKVwT, QKVb, VtB, nullptr, nullptr, W1, W2, W1T, W2T, 192);
  attn_part_k<<<dim3(1280), blk, 0, stream>>>(QKVb, VtB, Opart, lpart, attn);
  attn_combine_k<<<dim3(24, 16), blk, 0, stream>>>(Opart, lpart, attn);
  // proj: 128x128 split-K x2 (kc=512, NITER=16), 256 blocks (R6 form)
  gemm_bt_k<4, 0, 16><<<dim3(256), blk, 0, stream>>>(attn, WprojT, 1024, projp);
  proj_rms_k<<<dim3(2048), blk, 0, stream>>>(projp, bproj, x, g2, x1, xn2);
  // FFN1: wide 128x256, grid 256, SiLU fused
  gemm_wide_k<2, 32><<<dim3(256), blk, 0, stream>>>(
      xn2, W1T, hbuf, nullptr, nullptr, nullptr,
      nullptr, nullptr, nullptr, nullptr, 0);
  // FFN2: wide 128x256, split-K x8 (kc=512), grid 512
  gemm_wide_k<4, 16><<<dim3(512), blk, 0, stream>>>(
      hbuf, W2T, nullptr, nullptr, ffn2pA, ffn2pB,
      nullptr, nullptr, nullptr, nullptr, 0);
  reduce_ffn2_k<<<dim3(2048), blk, 0, stream>>>(ffn2pA, ffn2pB, x1, (float*)d_out);
}

// Round 12
// 243.560 us; speedup vs baseline: 1.0659x; 1.0395x over previous
//
#include <hip/hip_runtime.h>

typedef unsigned short u16;
typedef unsigned int u32;
typedef __attribute__((ext_vector_type(4))) float f32x4;
typedef __attribute__((ext_vector_type(8))) __bf16 bf16x8;

#define T_SEQ 2048
#define DMODEL 1024
#define NHEAD 16
#define HEADS 64
#define FFDIM 4096
#define MNQ 2097152l  // 2048*1024

__device__ __forceinline__ u16 f2bf(float f) {
  u32 u = __builtin_bit_cast(u32, f);
  u = u + 0x7FFFu + ((u >> 16) & 1u);
  return (u16)(u >> 16);
}
__device__ __forceinline__ float bf2f(u16 h) {
  u32 u = ((u32)h) << 16;
  return __builtin_bit_cast(float, u);
}
__device__ __forceinline__ void gload_lds16(const u16* g, u16* l) {
  __builtin_amdgcn_global_load_lds(
      (const __attribute__((address_space(1))) u32*)g,
      (__attribute__((address_space(3))) u32*)l, 16, 0, 0);
}

// Vectorized 64x64 transpose: float4 loads (1KB/wave), uint4 stores (16B/lane).
__device__ __forceinline__ void transpose64(const float* __restrict__ in,
                                            long ldin, u16* __restrict__ out,
                                            long ldout, int r0, int c0, int tid,
                                            u16* tile) {
#pragma unroll
  for (int p = 0; p < 4; ++p) {
    int idx = p * 256 + tid;
    int r = idx >> 4, c4 = (idx & 15) * 4;
    float4 v = *(const float4*)(in + (long)(r0 + r) * ldin + c0 + c4);
    tile[(c4 + 0) * 66 + r] = f2bf(v.x);
    tile[(c4 + 1) * 66 + r] = f2bf(v.y);
    tile[(c4 + 2) * 66 + r] = f2bf(v.z);
    tile[(c4 + 3) * 66 + r] = f2bf(v.w);
  }
  __syncthreads();
#pragma unroll
  for (int p = 0; p < 2; ++p) {
    int idx = p * 256 + tid;
    int c = idx >> 3, rg = (idx & 7) * 8;
    u16 tmp[8];
#pragma unroll
    for (int j = 0; j < 8; ++j) tmp[j] = tile[c * 66 + rg + j];
    *(uint4*)(out + (long)(c0 + c) * ldout + r0 + rg) = *(uint4*)tmp;
  }
}

// ------------- prep: QKV/Wproj weight transposes + RMSNorm1 -----------------
__global__ __launch_bounds__(256) void prep_k(
    const float* __restrict__ Wq, const float* __restrict__ Wk,
    const float* __restrict__ Wv, const float* __restrict__ Wproj,
    const float* __restrict__ x, const float* __restrict__ g1,
    u16* __restrict__ QKVwT, u16* __restrict__ WprojT, u16* __restrict__ xn1) {
  __shared__ u16 tile[64 * 66];
  __shared__ float wsum[4];
  int bid = blockIdx.x;
  int tid = threadIdx.x;
  if (bid >= 1024) {
    int row = bid - 1024;
    const float4* xr = (const float4*)(x + (long)row * DMODEL);
    float4 v = xr[tid];
    float ss = v.x * v.x + v.y * v.y + v.z * v.z + v.w * v.w;
#pragma unroll
    for (int off = 32; off >= 1; off >>= 1) ss += __shfl_xor(ss, off, 64);
    if ((tid & 63) == 0) wsum[tid >> 6] = ss;
    __syncthreads();
    float tot = wsum[0] + wsum[1] + wsum[2] + wsum[3];
    float rms = rsqrtf(tot * (1.0f / DMODEL) + 1e-6f);
    float4 gv = ((const float4*)g1)[tid];
    ushort4 o4 = make_ushort4(f2bf(v.x * rms * gv.x), f2bf(v.y * rms * gv.y),
                              f2bf(v.z * rms * gv.z), f2bf(v.w * rms * gv.w));
    ((ushort4*)(xn1 + (long)row * DMODEL))[tid] = o4;
    return;
  }
  const float* in;
  u16* out;
  long ldin, ldout;
  int r0, c0;
  if (bid < 768) {
    int z = bid >> 4, xi = bid & 15;
    int wsel = z >> 4, h = z & 15;
    in = (wsel == 0 ? Wq : (wsel == 1 ? Wk : Wv)) + (long)h * 65536;
    out = QKVwT + (long)wsel * 1048576 + (long)h * 65536;
    ldin = 64; ldout = 1024;
    r0 = xi * 64; c0 = 0;
  } else {
    int b = bid - 768;
    in = Wproj; out = WprojT; ldin = 1024; ldout = 1024;
    r0 = (b >> 4) * 64; c0 = (b & 15) * 64;
  }
  transpose64(in, ldin, out, ldout, r0, c0, tid, tile);
}

// ---- fused: proj split-K(x2, bf16 partials) reduce -> x1, RMSNorm -> xn2 ----
__global__ __launch_bounds__(256) void proj_rms_k(
    const u16* __restrict__ part, const float* __restrict__ bias,
    const float* __restrict__ resid, const float* __restrict__ g,
    float* __restrict__ x1, u16* __restrict__ xn2) {
  int row = blockIdx.x;
  int tid = threadIdx.x;
  long i = (long)row * DMODEL + tid * 4;
  float4 r = *(const float4*)(resid + i);
  float4 bi = *(const float4*)(bias + tid * 4);
  float4 v;
  v.x = r.x + bi.x; v.y = r.y + bi.y; v.z = r.z + bi.z; v.w = r.w + bi.w;
#pragma unroll
  for (int z = 0; z < 2; ++z) {
    ushort4 a = *(const ushort4*)(part + z * MNQ + i);
    v.x += bf2f(a.x); v.y += bf2f(a.y); v.z += bf2f(a.z); v.w += bf2f(a.w);
  }
  *(float4*)(x1 + i) = v;
  float ss = v.x * v.x + v.y * v.y + v.z * v.z + v.w * v.w;
#pragma unroll
  for (int off = 32; off >= 1; off >>= 1) ss += __shfl_xor(ss, off, 64);
  __shared__ float wsum[4];
  if ((tid & 63) == 0) wsum[tid >> 6] = ss;
  __syncthreads();
  float tot = wsum[0] + wsum[1] + wsum[2] + wsum[3];
  float rms = rsqrtf(tot * (1.0f / DMODEL) + 1e-6f);
  float4 gv = ((const float4*)g)[tid];
  ushort4 o4 = make_ushort4(f2bf(v.x * rms * gv.x), f2bf(v.y * rms * gv.y),
                            f2bf(v.z * rms * gv.z), f2bf(v.w * rms * gv.w));
  ((ushort4*)(xn2 + (long)row * DMODEL))[tid] = o4;
}

// ------- GEMM (128x128 tile, 3-stage, vmcnt(4)) — QKV (+fill) and proj ------
// MODE 0: partition n. EPI 0: bf16 (+V-transpose cols>=2048). 4: bf16 split-K
// partial.
template <int EPI, int MODE, int NITER, bool FILL = false>
__global__ __launch_bounds__(256, 3) void gemm_bt_k(
    const u16* __restrict__ A, const u16* __restrict__ Bt, int N,
    u16* __restrict__ out16, u16* __restrict__ vt,
    u16* __restrict__ p0, u16* __restrict__ p1,
    const float* __restrict__ F1, const float* __restrict__ F2,
    u16* __restrict__ FT1, u16* __restrict__ FT2, int ngemm) {
  __shared__ __align__(16) u16 As[3][128 * 32];
  __shared__ __align__(16) u16 Bs[3][128 * 32];
  if constexpr (FILL) {
    if ((int)blockIdx.x >= ngemm) {
      int tb = (int)blockIdx.x - ngemm;
      u16* tile = (u16*)As;
      const float* in;
      u16* out;
      long ldin, ldout;
      int r0, c0;
      if (tb < 1024) {
        in = F1; out = FT1; ldin = 4096; ldout = 1024;
        r0 = (tb & 15) * 64; c0 = (tb >> 4) * 64;
      } else {
        int b = tb - 1024;
        in = F2; out = FT2; ldin = 1024; ldout = 4096;
        r0 = (b >> 4) * 64; c0 = (b & 15) * 64;
      }
      transpose64(in, ldin, out, ldout, r0, c0, threadIdx.x, tile);
      return;
    }
  }
  const int K = 1024;
  const int kc = NITER * 32;
  int tid = threadIdx.x;
  int w = tid >> 6, lane = tid & 63;
  int quad = lane >> 4, l15 = lane & 15;
  int wr = w >> 1, wc = w & 1;

  int bid = blockIdx.x;
  int xcd = bid & 7, s = bid >> 3;
  int nn = N >> 7;
  int bx, by, kz;
  {
    int nl = nn >> 3;
    by = xcd * nl + s % nl;
    int r = s / nl;
    bx = r & 15;
    kz = r >> 4;
  }
  int m0 = bx * 128, n0 = by * 128;

  f32x4 acc[4][4] = {};

  int lr = lane >> 2;
  int sw = (lr >> 1) & 3;
  int lc = ((lane & 3) ^ sw) * 8;
  const u16* Ak = A + (long)(m0 + w * 32 + lr) * K + lc + (long)kz * kc;
  const u16* A2k = Ak + (long)16 * K;
  const u16* Bk = Bt + (long)(n0 + w * 32 + lr) * K + lc + (long)kz * kc;
  const u16* B2k = Bk + (long)16 * K;

  gload_lds16(Ak, As[0] + w * 1024);
  gload_lds16(A2k, As[0] + w * 1024 + 512);
  gload_lds16(Bk, Bs[0] + w * 1024);
  gload_lds16(B2k, Bs[0] + w * 1024 + 512);
  gload_lds16(Ak + 32, As[1] + w * 1024);
  gload_lds16(A2k + 32, As[1] + w * 1024 + 512);
  gload_lds16(Bk + 32, Bs[1] + w * 1024);
  gload_lds16(B2k + 32, Bs[1] + w * 1024 + 512);

  int swq = (l15 >> 1) & 3;
  int qoff = (quad ^ swq) << 3;

#pragma unroll
  for (int k = 0; k < NITER; ++k) {
    const int cb = k % 3;
    if (k + 2 < NITER) {
      asm volatile("s_waitcnt vmcnt(4)\n\ts_barrier" ::: "memory");
      const int pb = (k + 2) % 3;
      const int off = (k + 2) * 32;
      gload_lds16(Ak + off, As[pb] + w * 1024);
      gload_lds16(A2k + off, As[pb] + w * 1024 + 512);
      gload_lds16(Bk + off, Bs[pb] + w * 1024);
      gload_lds16(B2k + off, Bs[pb] + w * 1024 + 512);
    } else {
      asm volatile("s_waitcnt vmcnt(0)\n\ts_barrier" ::: "memory");
    }
    const u16* Ab = As[cb];
    const u16* Bb = Bs[cb];
    bf16x8 af[4], bfr[4];
#pragma unroll
    for (int mt = 0; mt < 4; ++mt)
      af[mt] = *(const bf16x8*)(Ab + (wr * 64 + mt * 16 + l15) * 32 + qoff);
#pragma unroll
    for (int nt = 0; nt < 4; ++nt)
      bfr[nt] = *(const bf16x8*)(Bb + (wc * 64 + nt * 16 + l15) * 32 + qoff);
#pragma unroll
    for (int mt = 0; mt < 4; ++mt)
#pragma unroll
      for (int nt = 0; nt < 4; ++nt)
        acc[mt][nt] = __builtin_amdgcn_mfma_f32_16x16x32_bf16(
            af[mt], bfr[nt], acc[mt][nt], 0, 0, 0);
  }

  bool vblock = (EPI == 0) && (vt != nullptr) && (n0 >= 2048);
  u16* pb = nullptr;
  if (EPI == 4) pb = p0 + (long)kz * MNQ;
#pragma unroll
  for (int mt = 0; mt < 4; ++mt)
#pragma unroll
    for (int nt = 0; nt < 4; ++nt) {
      int col = n0 + wc * 64 + nt * 16 + l15;
      if (EPI == 0 && vblock) {
        int sc = col - 2048;
        int row0 = m0 + wr * 64 + mt * 16 + quad * 4;
        ushort4 pk = make_ushort4(f2bf(acc[mt][nt][0]), f2bf(acc[mt][nt][1]),
                                  f2bf(acc[mt][nt][2]), f2bf(acc[mt][nt][3]));
        *(ushort4*)(vt + (long)sc * 2048 + row0) = pk;
        continue;
      }
#pragma unroll
      for (int r = 0; r < 4; ++r) {
        int row = m0 + wr * 64 + mt * 16 + quad * 4 + r;
        long idx = (long)row * N + col;
        float v = acc[mt][nt][r];
        if (EPI == 0) {
          out16[idx] = f2bf(v);
        } else if (EPI == 4) {
          pb[idx] = f2bf(v);
        }
      }
    }
}

// ------- wide-wave GEMM for FFN1/FFN2: 128x256 tile, 64x128 wave tile -------
template <int EPI, int NITER>
__global__ __launch_bounds__(256, 2) void gemm_wide_k(
    const u16* __restrict__ A, const u16* __restrict__ Bt,
    u16* __restrict__ out16, u16* __restrict__ p0, u16* __restrict__ p1) {
  __shared__ __align__(16) u16 As[3][128 * 32];
  __shared__ __align__(16) u16 Bs[3][256 * 32];
  const int K = (EPI == 4) ? 4096 : 1024;
  const int N = (EPI == 4) ? 1024 : 4096;
  const int kc = NITER * 32;
  int tid = threadIdx.x;
  int w = tid >> 6, lane = tid & 63;
  int quad = lane >> 4, l15 = lane & 15;
  int wr = w >> 1, wc = w & 1;

  int bid = blockIdx.x;
  int xcd = bid & 7, s = bid >> 3;
  int bx, by, kz;
  if (EPI == 2) {
    by = xcd * 2 + (s & 1);
    bx = s >> 1;
    kz = 0;
  } else {
    kz = xcd;
    by = s & 3;
    bx = s >> 2;
  }
  int m0 = bx * 128, n0 = by * 256;

  f32x4 acc[4][8] = {};

  int lr = lane >> 2;
  int sw = (lr >> 1) & 3;
  int lc = ((lane & 3) ^ sw) * 8;
  const u16* Ak = A + (long)(m0 + w * 32 + lr) * K + (long)kz * kc + lc;
  const u16* A2k = Ak + (long)16 * K;
  const u16* Bk0 = Bt + (long)(n0 + w * 64 + lr) * K + (long)kz * kc + lc;
  const u16* Bk1 = Bk0 + (long)16 * K;
  const u16* Bk2 = Bk0 + (long)32 * K;
  const u16* Bk3 = Bk0 + (long)48 * K;

#pragma unroll
  for (int t = 0; t < 2; ++t) {
    const int off = t * 32;
    gload_lds16(Ak + off, As[t] + w * 1024);
    gload_lds16(A2k + off, As[t] + w * 1024 + 512);
    gload_lds16(Bk0 + off, Bs[t] + w * 2048);
    gload_lds16(Bk1 + off, Bs[t] + w * 2048 + 512);
    gload_lds16(Bk2 + off, Bs[t] + w * 2048 + 1024);
    gload_lds16(Bk3 + off, Bs[t] + w * 2048 + 1536);
  }

  int swq = (l15 >> 1) & 3;
  int qoff = (quad ^ swq) << 3;

#pragma unroll
  for (int k = 0; k < NITER; ++k) {
    const int cb = k % 3;
    if (k + 2 < NITER) {
      asm volatile("s_waitcnt vmcnt(6)\n\ts_barrier" ::: "memory");
      const int pb2 = (k + 2) % 3;
      const int off = (k + 2) * 32;
      gload_lds16(Ak + off, As[pb2] + w * 1024);
      gload_lds16(A2k + off, As[pb2] + w * 1024 + 512);
      gload_lds16(Bk0 + off, Bs[pb2] + w * 2048);
      gload_lds16(Bk1 + off, Bs[pb2] + w * 2048 + 512);
      gload_lds16(Bk2 + off, Bs[pb2] + w * 2048 + 1024);
      gload_lds16(Bk3 + off, Bs[pb2] + w * 2048 + 1536);
    } else if (k + 2 == NITER) {
      asm volatile("s_waitcnt vmcnt(6)\n\ts_barrier" ::: "memory");
    } else {
      asm volatile("s_waitcnt vmcnt(0)\n\ts_barrier" ::: "memory");
    }
    const u16* Ab = As[cb];
    const u16* Bb = Bs[cb];
    bf16x8 af[4], bfr[8];
#pragma unroll
    for (int mt = 0; mt < 4; ++mt)
      af[mt] = *(const bf16x8*)(Ab + (wr * 64 + mt * 16 + l15) * 32 + qoff);
#pragma unroll
    for (int nt = 0; nt < 8; ++nt)
      bfr[nt] = *(const bf16x8*)(Bb + (wc * 128 + nt * 16 + l15) * 32 + qoff);
#pragma unroll
    for (int mt = 0; mt < 4; ++mt)
#pragma unroll
      for (int nt = 0; nt < 8; ++nt)
        acc[mt][nt] = __builtin_amdgcn_mfma_f32_16x16x32_bf16(
            af[mt], bfr[nt], acc[mt][nt], 0, 0, 0);
  }

  u16* pb = nullptr;
  if (EPI == 4)
    pb = (kz < 4) ? (p0 + (long)kz * MNQ) : (p1 + (long)(kz - 4) * MNQ);
#pragma unroll
  for (int mt = 0; mt < 4; ++mt)
#pragma unroll
    for (int nt = 0; nt < 8; ++nt) {
      int col = n0 + wc * 128 + nt * 16 + l15;
#pragma unroll
      for (int r = 0; r < 4; ++r) {
        int row = m0 + wr * 64 + mt * 16 + quad * 4 + r;
        float v = acc[mt][nt][r];
        if (EPI == 2) {
          out16[(long)row * N + col] = f2bf(v / (1.0f + __expf(-v)));
        } else {
          pb[(long)row * N + col] = f2bf(v);
        }
      }
    }
}

// ---------------- FFN2 split-K(x8) reduce (bf16 partials) ----------------
__global__ __launch_bounds__(256) void reduce_ffn2_k(
    const u16* __restrict__ p0, const u16* __restrict__ p1,
    const float* __restrict__ resid, float* __restrict__ out) {
  long i = ((long)blockIdx.x * 256 + threadIdx.x) * 4;
  float4 r = *(const float4*)(resid + i);
  float4 o = r;
#pragma unroll
  for (int z = 0; z < 4; ++z) {
    ushort4 a = *(const ushort4*)(p0 + z * MNQ + i);
    ushort4 b = *(const ushort4*)(p1 + z * MNQ + i);
    o.x += bf2f(a.x) + bf2f(b.x);
    o.y += bf2f(a.y) + bf2f(b.y);
    o.z += bf2f(a.z) + bf2f(b.z);
    o.w += bf2f(a.w) + bf2f(b.w);
  }
  *(float4*)(out + i) = o;
}

// ------- split-KV flash attention, S^T trick + XCD-aware head placement -----
#define LSTR 72
__global__ __launch_bounds__(256) void attn_part_k(const u16* __restrict__ QKV,
                                                   const u16* __restrict__ Vt,
                                                   u16* __restrict__ Opart,
                                                   float* __restrict__ lpart,
                                                   u16* __restrict__ attn) {
  __shared__ __align__(16) u16 Qs[64 * LSTR];  // aliased as P after aq read
  __shared__ __align__(16) u16 Ks[64 * LSTR];
  __shared__ __align__(16) u16 Vs[64 * LSTR];
  __shared__ float lbuf[64];

  int tid = threadIdx.x;
  int w = tid >> 6, lane = tid & 63;
  int quad = lane >> 4, l15 = lane & 15;

  int bid = blockIdx.x;
  int xcd = bid & 7, sg = bid >> 3;
  int h = xcd * 2 + (sg & 1);
  int p = sg >> 1;

  int bx = 0, acc0 = 0;
  while (true) {
    int n = (bx >> 3) + 1;
    if (p < acc0 + n) break;
    acc0 += n;
    ++bx;
  }
  int c = p - acc0;
  int t0 = bx * 64;
  int jstart = c * 8;
  int jend = min(jstart + 8, bx + 1);

#pragma unroll
  for (int pp = 0; pp < 2; ++pp) {
    int idx = pp * 256 + tid;
    int row = idx >> 3, cc = idx & 7;
    *(uint4*)(Qs + row * LSTR + cc * 8) =
        *(const uint4*)(QKV + (long)(t0 + row) * 3072 + h * 64 + cc * 8);
  }
  __syncthreads();
  bf16x8 aq[2];
#pragma unroll
  for (int ks = 0; ks < 2; ++ks)
    aq[ks] = *(const bf16x8*)(Qs + (w * 16 + l15) * LSTR + ks * 32 + quad * 8);

  f32x4 oacc[4] = {};
  float lsum = 0.f;
  int qg = t0 + w * 16 + l15;

  u16* PsW = Qs + w * (16 * LSTR);

  for (int j = jstart; j < jend; ++j) {
    __syncthreads();
#pragma unroll
    for (int pp = 0; pp < 2; ++pp) {
      int idx = pp * 256 + tid;
      int row = idx >> 3, cc = idx & 7;
      *(uint4*)(Ks + row * LSTR + cc * 8) =
          *(const uint4*)(QKV + (long)(j * 64 + row) * 3072 + 1024 + h * 64 + cc * 8);
      *(uint4*)(Vs + row * LSTR + cc * 8) =
          *(const uint4*)(Vt + (long)h * (64 * 2048) + (long)row * 2048 + j * 64 + cc * 8);
    }
    __syncthreads();

    f32x4 sacc[4] = {};
#pragma unroll
    for (int ks = 0; ks < 2; ++ks)
#pragma unroll
      for (int ut = 0; ut < 4; ++ut) {
        bf16x8 kf = *(const bf16x8*)(Ks + (ut * 16 + l15) * LSTR + ks * 32 + quad * 8);
        sacc[ut] = __builtin_amdgcn_mfma_f32_16x16x32_bf16(kf, aq[ks], sacc[ut], 0, 0, 0);
      }

    bool boundary = (j == bx);
#pragma unroll
    for (int ut = 0; ut < 4; ++ut) {
      float pv[4];
#pragma unroll
      for (int r = 0; r < 4; ++r) {
        float v = exp2f(sacc[ut][r] * 0.18033688f);
        if (boundary) {
          int u = j * 64 + ut * 16 + quad * 4 + r;
          if (u > qg) v = 0.f;
        }
        pv[r] = v;
        lsum += v;
      }
      ushort4 pk = make_ushort4(f2bf(pv[0]), f2bf(pv[1]), f2bf(pv[2]), f2bf(pv[3]));
      *(ushort4*)(PsW + l15 * LSTR + ut * 16 + quad * 4) = pk;
    }
    asm volatile("s_waitcnt lgkmcnt(0)" ::: "memory");
#pragma unroll
    for (int ks = 0; ks < 2; ++ks) {
      bf16x8 pf = *(const bf16x8*)(PsW + l15 * LSTR + ks * 32 + quad * 8);
#pragma unroll
      for (int ct = 0; ct < 4; ++ct) {
        bf16x8 vf = *(const bf16x8*)(Vs + (ct * 16 + l15) * LSTR + ks * 32 + quad * 8);
        oacc[ct] = __builtin_amdgcn_mfma_f32_16x16x32_bf16(pf, vf, oacc[ct], 0, 0, 0);
      }
    }
  }

  lsum += __shfl_xor(lsum, 16, 64);
  lsum += __shfl_xor(lsum, 32, 64);
  if (quad == 0) lbuf[w * 16 + l15] = 1.0f / lsum;
  asm volatile("s_waitcnt lgkmcnt(0)" ::: "memory");

  float inv[4];
#pragma unroll
  for (int r = 0; r < 4; ++r) inv[r] = lbuf[w * 16 + quad * 4 + r];

  if (bx < 8) {
#pragma unroll
    for (int ct = 0; ct < 4; ++ct)
#pragma unroll
      for (int r = 0; r < 4; ++r)
        attn[(long)(t0 + w * 16 + quad * 4 + r) * 1024 + h * 64 + ct * 16 + l15] =
            f2bf(oacc[ct][r] * inv[r]);
    return;
  }
  long slot = (long)p * 16 + h;
  u16* Ob = Opart + slot * 4096;
#pragma unroll
  for (int ct = 0; ct < 4; ++ct)
#pragma unroll
    for (int r = 0; r < 4; ++r)
      Ob[(w * 16 + quad * 4 + r) * 64 + ct * 16 + l15] = f2bf(oacc[ct][r] * inv[r]);
  if (quad == 0) lpart[slot * 64 + w * 16 + l15] = lsum;
}

// ---------------- combine partials (bx >= 8 only) ----------------
__global__ __launch_bounds__(256) void attn_combine_k(
    const u16* __restrict__ Opart, const float* __restrict__ lpart,
    u16* __restrict__ out) {
  int bx = blockIdx.x + 8, h = blockIdx.y;
  int g = bx >> 3;
  int p0 = 4 * g * (g + 1) + (bx - 8 * g) * (g + 1);
  int nc = g + 1;
  int tid = threadIdx.x;
  int row = tid >> 2, c4 = (tid & 3) * 16;

  float lv[4];
  float wsum = 0.f;
  for (int cidx = 0; cidx < nc; ++cidx) {
    long slot = (long)(p0 + cidx) * 16 + h;
    lv[cidx] = lpart[slot * 64 + row];
    wsum += lv[cidx];
  }
  float rinv = 1.0f / wsum;

  float o[16];
#pragma unroll
  for (int i = 0; i < 16; ++i) o[i] = 0.f;
  for (int cidx = 0; cidx < nc; ++cidx) {
    float wc = lv[cidx] * rinv;
    const u16* Ob = Opart + ((long)(p0 + cidx) * 16 + h) * 4096 + row * 64 + c4;
    bf16x8 a = *(const bf16x8*)Ob;
    bf16x8 b = *(const bf16x8*)(Ob + 8);
#pragma unroll
    for (int i = 0; i < 8; ++i) {
      o[i] += wc * (float)a[i];
      o[8 + i] += wc * (float)b[i];
    }
  }
  u16 ob[16];
#pragma unroll
  for (int i = 0; i < 16; ++i) ob[i] = f2bf(o[i]);
  u16* op = out + (long)(bx * 64 + row) * 1024 + h * 64 + c4;
  *(uint4*)op = *(uint4*)ob;
  *(uint4*)(op + 8) = *(uint4*)(ob + 8);
}

// ---------------- launch ----------------
extern "C" void kernel_launch(void* const* d_in, const int* in_sizes, int n_in,
                              void* d_out, int out_size, void* d_ws, size_t ws_size,
                              hipStream_t stream) {
  const float* x     = (const float*)d_in[0];
  const float* Wq    = (const float*)d_in[1];
  const float* Wk    = (const float*)d_in[2];
  const float* Wv    = (const float*)d_in[3];
  const float* Wproj = (const float*)d_in[4];
  const float* bproj = (const float*)d_in[5];
  const float* W1    = (const float*)d_in[6];
  const float* W2    = (const float*)d_in[7];
  const float* g1    = (const float*)d_in[8];
  const float* g2    = (const float*)d_in[9];

  char* ws = (char*)d_ws;
  u16* QKVwT  = (u16*)(ws);                   // 0..6 MiB
  u16* WprojT = (u16*)(ws + (6ul << 20));     // 6..8
  u16* W1T    = (u16*)(ws + (8ul << 20));     // 8..16
  u16* W2T    = (u16*)(ws + (16ul << 20));    // 16..24 (live thru FFN2)
  u16* xn1    = (u16*)(ws + (24ul << 20));    // 24..28
  u16* QKVb   = (u16*)(ws + (28ul << 20));    // 28..40
  u16* VtB    = (u16*)(ws + (40ul << 20));    // 40..44
  u16* attn   = (u16*)(ws + (44ul << 20));    // 44..48
  float* x1   = (float*)(ws + (48ul << 20));  // 48..56
  u16* xn2    = (u16*)(ws + (56ul << 20));    // 56..60
  u16* hbuf   = (u16*)(ws + (60ul << 20));    // 60..76
  // aliases (dead-region reuse):
  u16* Opart    = (u16*)(ws + (48ul << 20));  // 48..58 (dead before proj_rms)
  float* lpart  = (float*)(ws + (58ul << 20));// 58..58.4
  u16* projp    = (u16*)(ws + (28ul << 20));  // 28..36: 2 x 4 MiB bf16 partials
  u16* ffn2pA   = (u16*)(ws + (28ul << 20));  // 28..44: kz 0..3 (QKVb/VtB dead)
  u16* ffn2pB   = (u16*)(ws);                 // 0..16: kz 4..7 (weights dead)
  if (ws_size < (76ul << 20)) return;

  dim3 blk(256);

  // prep: 768 QKVw + 256 Wproj transposes + 2048 rmsnorm rows
  prep_k<<<dim3(3072), blk, 0, stream>>>(
      Wq, Wk, Wv, Wproj, x, g1, QKVwT, WprojT, xn1);
  // QKV: 384 gemm blocks (128x128, K=1024) + 2048 W1/W2 transpose fillers
  gemm_bt_k<0, 0, 32, true><<<dim3(2432), blk, 0, stream>>>(
      xn1, QKVwT, 3072, QKVb, VtB, nullptr, nullptr, W1, W2, W1T, W2T, 384);
  attn_part_k<<<dim3(1280), blk, 0, stream>>>(QKVb, VtB, Opart, lpart, attn);
  attn_combine_k<<<dim3(24, 16), blk, 0, stream>>>(Opart, lpart, attn);
  // proj: split-K x2 (kc=512, NITER=16), 256 blocks
  gemm_bt_k<4, 0, 16><<<dim3(256), blk, 0, stream>>>(
      attn, WprojT, 1024, nullptr, nullptr, projp, nullptr,
      nullptr, nullptr, nullptr, nullptr, 0);
  proj_rms_k<<<dim3(2048), blk, 0, stream>>>(projp, bproj, x, g2, x1, xn2);
  // FFN1: wide-wave 128x256, grid 256 (1 block/CU), SiLU fused
  gemm_wide_k<2, 32><<<dim3(256), blk, 0, stream>>>(
      xn2, W1T, hbuf, nullptr, nullptr);
  // FFN2: wide-wave 128x256, split-K x8 (kc=512), grid 512 (2 blocks/CU)
  gemm_wide_k<4, 16><<<dim3(512), blk, 0, stream>>>(
      hbuf, W2T, nullptr, ffn2pA, ffn2pB);
  reduce_ffn2_k<<<dim3(2048), blk, 0, stream>>>(ffn2pA, ffn2pB, x1, (float*)d_out);
}